// Round 4
// baseline (74.249 us; speedup 1.0000x reference)
//
#include <hip/hip_runtime.h>
#include <hip/hip_bf16.h>

typedef __attribute__((ext_vector_type(8))) short bf16x8;
typedef __attribute__((ext_vector_type(4))) float f32x4;

constexpr int L  = 128;
constexpr int BK = 128;              // bf16 columns staged per chunk
constexpr int LDS_PITCH = BK * 2;    // 256 bytes per row
constexpr int GRID = 512;            // 2 blocks/CU at 64 KB LDS

__device__ inline bf16x8 ld_frag(const char* lds, int row, int kk, int lane) {
    int byteoff = row * LDS_PITCH + (kk + 8 * (lane >> 4)) * 2;
    byteoff ^= (row & 7) << 4;       // same XOR swizzle as the write side
    return *reinterpret_cast<const bf16x8*>(lds + byteoff);
}

__global__ __launch_bounds__(256, 2)
void gram_kernel(const float* __restrict__ slots, uint4* __restrict__ pT,
                 unsigned* __restrict__ counter, int D, int nChunks, int G) {
    __shared__ __align__(16) char smem[2][L * LDS_PITCH];   // 2 x 32 KB
    const int t    = threadIdx.x;
    const int wave = t >> 6;
    const int lane = t & 63;

    if (blockIdx.x == 0 && t == 0) *counter = 0;   // ticket for reduce_finalize

    f32x4 acc[2][8];
#pragma unroll
    for (int r = 0; r < 2; ++r)
#pragma unroll
        for (int c = 0; c < 8; ++c) acc[r][c] = (f32x4)0.f;

    float4 ld[16];

    auto issue = [&](int chunk) {
        const size_t c0 = (size_t)chunk * BK;
#pragma unroll
        for (int q = 0; q < 16; ++q) {
            int idx  = t + 256 * q;          // 0..4095
            int row  = idx >> 5;
            int col4 = idx & 31;
            ld[q] = *reinterpret_cast<const float4*>(
                slots + (size_t)row * D + c0 + (size_t)col4 * 4);
        }
    };
    auto commit = [&](int buf) {
#pragma unroll
        for (int q = 0; q < 16; ++q) {
            int idx  = t + 256 * q;
            int row  = idx >> 5;
            int col4 = idx & 31;
            const unsigned int* f = reinterpret_cast<const unsigned int*>(&ld[q]);
            uint2 p;
            // truncate f32 -> bf16: high 16 bits, lo16 = elem0, hi16 = elem1
            p.x = __builtin_amdgcn_perm(f[1], f[0], 0x07060302u);
            p.y = __builtin_amdgcn_perm(f[3], f[2], 0x07060302u);
            int byteoff = row * LDS_PITCH + col4 * 8;
            byteoff ^= (row & 7) << 4;
            *reinterpret_cast<uint2*>(&smem[buf][0] + byteoff) = p;
        }
    };

    issue(blockIdx.x);
    commit(0);
    __syncthreads();

    int k = 0;
    for (int c = blockIdx.x; c < nChunks; c += G, ++k) {
        const int nxt = c + G;
        if (nxt < nChunks) issue(nxt);       // prefetch overlaps MFMA below
        const int cur = k & 1;

#pragma unroll
        for (int kk = 0; kk < BK; kk += 32) {
            bf16x8 a0 = ld_frag(&smem[cur][0], wave * 32 +      (lane & 15), kk, lane);
            bf16x8 a1 = ld_frag(&smem[cur][0], wave * 32 + 16 + (lane & 15), kk, lane);
#pragma unroll
            for (int cc = 0; cc < 8; ++cc) {
                bf16x8 b = ld_frag(&smem[cur][0], cc * 16 + (lane & 15), kk, lane);
                acc[0][cc] = __builtin_amdgcn_mfma_f32_16x16x32_bf16(a0, b, acc[0][cc], 0, 0, 0);
                acc[1][cc] = __builtin_amdgcn_mfma_f32_16x16x32_bf16(a1, b, acc[1][cc], 0, 0, 0);
            }
        }

        if (nxt < nChunks) commit(cur ^ 1);
        __syncthreads();
    }

    // ---- transposed bf16 partial writeout: pT[slot][block], slot = (r*4+c2)*256 + t
#pragma unroll
    for (int r = 0; r < 2; ++r)
#pragma unroll
        for (int c2 = 0; c2 < 4; ++c2) {
            const unsigned* e = reinterpret_cast<const unsigned*>(&acc[r][2 * c2]);
            const unsigned* o = reinterpret_cast<const unsigned*>(&acc[r][2 * c2 + 1]);
            uint4 u;
            u.x = __builtin_amdgcn_perm(e[1], e[0], 0x07060302u);  // lo=reg0, hi=reg1
            u.y = __builtin_amdgcn_perm(e[3], e[2], 0x07060302u);  // lo=reg2, hi=reg3
            u.z = __builtin_amdgcn_perm(o[1], o[0], 0x07060302u);
            u.w = __builtin_amdgcn_perm(o[3], o[2], 0x07060302u);
            int s = (r * 4 + c2) * 256 + t;
            pT[(size_t)s * G + blockIdx.x] = u;
        }
}

__device__ inline float blo(unsigned w) { unsigned v = w << 16;          return __builtin_bit_cast(float, v); }
__device__ inline float bhi(unsigned w) { unsigned v = w & 0xffff0000u;  return __builtin_bit_cast(float, v); }

// 256 blocks x 256 threads. Each 32-lane group owns one slot (coalesced 512B reads),
// single-writer gram (no atomics, no zeroing). Last block finalizes.
__global__ __launch_bounds__(256)
void reduce_finalize(const uint4* __restrict__ pT, float* __restrict__ gram,
                     unsigned* __restrict__ counter,
                     const float* __restrict__ temperature, float* __restrict__ out,
                     int G) {
    __shared__ float norms[L];
    __shared__ float wred[4];
    __shared__ unsigned ticket_s;
    const int t  = threadIdx.x;
    const int g  = t >> 5;           // 8 groups of 32 lanes
    const int ln = t & 31;
    const int s  = blockIdx.x * 8 + g;    // slot 0..2047

    float a8[8];
#pragma unroll
    for (int j = 0; j < 8; ++j) a8[j] = 0.f;

    const uint4* base = pT + (size_t)s * G;
#pragma unroll 16
    for (int p = ln; p < G; p += 32) {
        uint4 u = base[p];
        a8[0] += blo(u.x); a8[1] += bhi(u.x);
        a8[2] += blo(u.y); a8[3] += bhi(u.y);
        a8[4] += blo(u.z); a8[5] += bhi(u.z);
        a8[6] += blo(u.w); a8[7] += bhi(u.w);
    }
#pragma unroll
    for (int m = 1; m <= 16; m <<= 1)
#pragma unroll
        for (int j = 0; j < 8; ++j) a8[j] += __shfl_xor(a8[j], m);

    if (ln == 0) {
        // decode slot -> gram coords (matches gram_kernel pack)
        const int rc = s >> 8, tenc = s & 255;
        const int r = rc >> 2, c2 = rc & 3;
        const int wv = tenc >> 6, le = tenc & 63;
        const int growb = wv * 32 + r * 16 + ((le >> 4) << 2);
        const int gE = (2 * c2) * 16 + (le & 15);
#pragma unroll
        for (int j = 0; j < 4; ++j) {
            gram[(growb + j) * L + gE]      = a8[j];
            gram[(growb + j) * L + gE + 16] = a8[4 + j];
        }
    }

    __syncthreads();
    if (t == 0) {
        __threadfence();
        ticket_s = atomicAdd(counter, 1u);
    }
    __syncthreads();
    if (ticket_s != (unsigned)(gridDim.x - 1)) return;
    __threadfence();

    // ---------------- finalize (this block only) ----------------
    if (t < L) norms[t] = sqrtf(gram[t * L + t]);
    __syncthreads();

    const float invT = 1.0f / temperature[0];
    const int r = t >> 1;            // row, 2 threads per row
    const int q = t & 1;
    const float ni = norms[r];

    float ps = 0.f;
    for (int j = q; j < L; j += 2) {
        float sim = gram[r * L + j] / fmaxf(ni * norms[j], 1e-6f);
        ps += __expf(sim * invT);
    }
    ps += __shfl_xor(ps, 1);
    const float rowsum = ps;

    float tot = 0.f;
    for (int j = q; j < L; j += 2) {
        if (j > r) {
            float logit = (gram[r * L + j] / fmaxf(ni * norms[j], 1e-6f)) * invT;
            tot += -(logit - __logf(rowsum - __expf(logit))) * (float)(j - r);
        }
    }
#pragma unroll
    for (int m = 1; m < 64; m <<= 1) tot += __shfl_xor(tot, m);
    if ((t & 63) == 0) wred[t >> 6] = tot;
    __syncthreads();
    if (t == 0)
        out[0] = (wred[0] + wred[1] + wred[2] + wred[3]) /
                 ((float)(L - 1) * (float)(L - 1) * 0.5f);
}

extern "C" void kernel_launch(void* const* d_in, const int* in_sizes, int n_in,
                              void* d_out, int out_size, void* d_ws, size_t ws_size,
                              hipStream_t stream) {
    const float* slots       = (const float*)d_in[0];
    const float* temperature = (const float*)d_in[1];
    float* out  = (float*)d_out;

    const int D = in_sizes[0] / L;                  // 262144
    const int nChunks = D / BK;                     // 2048
    int G = GRID;
    if (G > nChunks) G = nChunks;

    uint4*    pT      = (uint4*)d_ws;                                   // 2048*G*16B
    float*    gram    = (float*)((char*)d_ws + (size_t)2048 * G * 16);  // 64 KB
    unsigned* counter = (unsigned*)((char*)gram + (size_t)L * L * 4);

    gram_kernel<<<G, 256, 0, stream>>>(slots, pT, counter, D, nChunks, G);
    reduce_finalize<<<256, 256, 0, stream>>>(pT, gram, counter, temperature, out, G);
}

// Round 5
// 59.605 us; speedup vs baseline: 1.2457x; 1.2457x over previous
//
#include <hip/hip_runtime.h>
#include <hip/hip_bf16.h>

typedef __attribute__((ext_vector_type(8))) short bf16x8;
typedef __attribute__((ext_vector_type(4))) float f32x4;

constexpr int L  = 128;
constexpr int BK = 64;               // f32 columns staged per chunk
constexpr int GRID = 512;            // 2 blocks/CU (64 KB LDS each)

__device__ inline float blo(unsigned w) { unsigned v = w << 16;          return __builtin_bit_cast(float, v); }
__device__ inline float bhi(unsigned w) { unsigned v = w & 0xffff0000u;  return __builtin_bit_cast(float, v); }

// LDS f32 tile [128][64]; LDS unit (row,u) holds global unit (row, u^(row&15)).
// Source-swizzled global_load_lds (linear dest), reads apply the same XOR.
__global__ __launch_bounds__(256, 2)
void gram_kernel(const float* __restrict__ slots, unsigned* __restrict__ p16,
                 unsigned* __restrict__ counter, int D, int nChunks, int G) {
    __shared__ __align__(16) float lbuf[2][L * BK];   // 2 x 32 KB
    const int t    = threadIdx.x;
    const int wave = t >> 6;
    const int lane = t & 63;

    if (blockIdx.x == 0 && t == 0) *counter = 0;     // ticket for reduce_finalize

    f32x4 acc[2][8];
#pragma unroll
    for (int r = 0; r < 2; ++r)
#pragma unroll
        for (int c = 0; c < 8; ++c) acc[r][c] = (f32x4)0.f;

    // stage one 128x64 f32 tile: 8 global_load_lds(16B) per wave
    auto stage = [&](int buf, int chunk) {
        const size_t cbyte = (size_t)chunk * (BK * 4);
#pragma unroll
        for (int q = 0; q < 8; ++q) {
            const int rowidx = (wave * 8 + q) * 4 + (lane >> 4);     // 4 rows / issue
            const int gu     = (lane & 15) ^ (rowidx & 15);          // source swizzle
            const char* src  = (const char*)slots +
                               (size_t)rowidx * D * 4 + cbyte + (size_t)gu * 16;
            __builtin_amdgcn_global_load_lds(
                (const __attribute__((address_space(1))) unsigned*)src,
                (__attribute__((address_space(3))) unsigned*)&lbuf[buf][(wave * 8 + q) * 256],
                16, 0, 0);
        }
    };

    // fragment: 8 bf16 of row `row`, k = kk + (lane>>4)*8 .. +7, via 2 f32 b128 reads
    auto ldfrag = [&](const float* base, int row, int kk) -> bf16x8 {
        const int u0 = (kk >> 2) + ((lane >> 4) << 1);               // even unit
        const int p0 = u0 ^ (row & 15);
        const int p1 = (u0 + 1) ^ (row & 15);
        const f32x4 f0 = *reinterpret_cast<const f32x4*>(base + row * BK + p0 * 4);
        const f32x4 f1 = *reinterpret_cast<const f32x4*>(base + row * BK + p1 * 4);
        const unsigned* a = reinterpret_cast<const unsigned*>(&f0);
        const unsigned* b = reinterpret_cast<const unsigned*>(&f1);
        union { bf16x8 v; unsigned w[4]; } r;
        r.w[0] = __builtin_amdgcn_perm(a[1], a[0], 0x07060302u);     // trunc f32->bf16
        r.w[1] = __builtin_amdgcn_perm(a[3], a[2], 0x07060302u);
        r.w[2] = __builtin_amdgcn_perm(b[1], b[0], 0x07060302u);
        r.w[3] = __builtin_amdgcn_perm(b[3], b[2], 0x07060302u);
        return r.v;
    };

    stage(0, blockIdx.x);
    __syncthreads();

    int k = 0;
    for (int c = blockIdx.x; c < nChunks; c += G, ++k) {
        const int cur = k & 1;
        if (c + G < nChunks) stage(cur ^ 1, c + G);   // prefetch next tile

#pragma unroll
        for (int kk = 0; kk < BK; kk += 32) {
            bf16x8 a0 = ldfrag(&lbuf[cur][0], wave * 32 +      (lane & 15), kk);
            bf16x8 a1 = ldfrag(&lbuf[cur][0], wave * 32 + 16 + (lane & 15), kk);
#pragma unroll
            for (int cc = 0; cc < 8; ++cc) {
                bf16x8 b = ldfrag(&lbuf[cur][0], cc * 16 + (lane & 15), kk);
                acc[0][cc] = __builtin_amdgcn_mfma_f32_16x16x32_bf16(a0, b, acc[0][cc], 0, 0, 0);
                acc[1][cc] = __builtin_amdgcn_mfma_f32_16x16x32_bf16(a1, b, acc[1][cc], 0, 0, 0);
            }
        }
        __syncthreads();   // drains gll vmcnt: next buffer ready; cur safe to overwrite
    }

    // ---- coalesced bf16 partial writeout: uint2 slot j = (r*8+c)*256 + t ----
    unsigned* pb = p16 + (size_t)blockIdx.x * 8192;   // 32 KB per block
#pragma unroll
    for (int r = 0; r < 2; ++r)
#pragma unroll
        for (int c = 0; c < 8; ++c) {
            const unsigned* a = reinterpret_cast<const unsigned*>(&acc[r][c]);
            uint2 w;
            w.x = __builtin_amdgcn_perm(a[1], a[0], 0x07060302u);   // lo=reg0 hi=reg1
            w.y = __builtin_amdgcn_perm(a[3], a[2], 0x07060302u);   // lo=reg2 hi=reg3
            *reinterpret_cast<uint2*>(pb + (((r * 8 + c) * 256 + t) << 1)) = w;
        }
}

// 128 blocks x 256 threads; block owns 32 uint2-slots; 8 sub-waves split the b-range.
// Single-writer gram (no atomics, no zeroing). Last block (ticket) finalizes.
__global__ __launch_bounds__(256)
void reduce_finalize(const unsigned* __restrict__ p16, float* __restrict__ gram,
                     unsigned* __restrict__ counter,
                     const float* __restrict__ temperature, float* __restrict__ out,
                     int G) {
    __shared__ f32x4 red[8][32];
    __shared__ float norms[L];
    __shared__ float wred[4];
    __shared__ unsigned ticket_s;
    const int t   = threadIdx.x;
    const int sub = t >> 5;
    const int sl  = t & 31;
    const int j   = blockIdx.x * 32 + sl;       // uint2 slot 0..4095

    const uint2* pt2 = reinterpret_cast<const uint2*>(p16);
    f32x4 s = (f32x4)0.f;
#pragma unroll 8
    for (int b = sub; b < G; b += 8) {
        const uint2 u = pt2[(size_t)b * 4096 + j];
        s[0] += blo(u.x); s[1] += bhi(u.x);
        s[2] += blo(u.y); s[3] += bhi(u.y);
    }
    red[sub][sl] = s;
    __syncthreads();
    if (t < 32) {
        f32x4 s4 = red[0][t];
#pragma unroll
        for (int w = 1; w < 8; ++w) s4 += red[w][t];
        const int myj  = blockIdx.x * 32 + t;
        const int slot = myj >> 8, tenc = myj & 255;
        const int wv = tenc >> 6, ln = tenc & 63;
        const int r = slot >> 3, c = slot & 7;
        const int growb = wv * 32 + r * 16 + ((ln >> 4) << 2);
        const int gcol  = c * 16 + (ln & 15);
#pragma unroll
        for (int q = 0; q < 4; ++q) gram[(growb + q) * L + gcol] = s4[q];
    }

    __syncthreads();
    if (t == 0) {
        __threadfence();
        ticket_s = atomicAdd(counter, 1u);
    }
    __syncthreads();
    if (ticket_s != (unsigned)(gridDim.x - 1)) return;
    __threadfence();

    // ---------------- finalize (last block only) ----------------
    if (t < L) norms[t] = sqrtf(gram[t * L + t]);
    __syncthreads();

    const float invT = 1.0f / temperature[0];
    const int r = t >> 1;            // row, 2 threads per row
    const int q = t & 1;
    const float ni = norms[r];

    float ps = 0.f;
    for (int jj = q; jj < L; jj += 2) {
        float sim = gram[r * L + jj] / fmaxf(ni * norms[jj], 1e-6f);
        ps += __expf(sim * invT);
    }
    ps += __shfl_xor(ps, 1);
    const float rowsum = ps;

    float tot = 0.f;
    for (int jj = q; jj < L; jj += 2) {
        if (jj > r) {
            float logit = (gram[r * L + jj] / fmaxf(ni * norms[jj], 1e-6f)) * invT;
            tot += -(logit - __logf(rowsum - __expf(logit))) * (float)(jj - r);
        }
    }
#pragma unroll
    for (int m = 1; m < 64; m <<= 1) tot += __shfl_xor(tot, m);
    if ((t & 63) == 0) wred[t >> 6] = tot;
    __syncthreads();
    if (t == 0)
        out[0] = (wred[0] + wred[1] + wred[2] + wred[3]) /
                 ((float)(L - 1) * (float)(L - 1) * 0.5f);
}

extern "C" void kernel_launch(void* const* d_in, const int* in_sizes, int n_in,
                              void* d_out, int out_size, void* d_ws, size_t ws_size,
                              hipStream_t stream) {
    const float* slots       = (const float*)d_in[0];
    const float* temperature = (const float*)d_in[1];
    float* out  = (float*)d_out;

    const int D = in_sizes[0] / L;                  // 262144
    const int nChunks = D / BK;                     // 4096
    int G = GRID;
    if (G > nChunks) G = nChunks;

    unsigned* p16     = (unsigned*)d_ws;                                 // G*32 KB = 16 MB
    float*    gram    = (float*)((char*)d_ws + (size_t)G * 32768);       // 64 KB
    unsigned* counter = (unsigned*)((char*)gram + (size_t)L * L * 4);

    gram_kernel<<<G, 256, 0, stream>>>(slots, p16, counter, D, nChunks, G);
    reduce_finalize<<<128, 256, 0, stream>>>(p16, gram, counter, temperature, out, G);
}

// Round 6
// 58.872 us; speedup vs baseline: 1.2612x; 1.0124x over previous
//
#include <hip/hip_runtime.h>
#include <hip/hip_bf16.h>

typedef __attribute__((ext_vector_type(8))) short bf16x8;
typedef __attribute__((ext_vector_type(4))) float f32x4;

constexpr int L     = 128;
constexpr int BK    = 64;            // f32 columns per chunk (stored bf16 in LDS)
constexpr int GRID  = 512;           // 2 blocks/CU, 16 waves/CU
constexpr int PITCH = BK * 2;        // 128 B per LDS row

__device__ inline float blo(unsigned w) { unsigned v = w << 16;          return __builtin_bit_cast(float, v); }
__device__ inline float bhi(unsigned w) { unsigned v = w & 0xffff0000u;  return __builtin_bit_cast(float, v); }

__global__ __launch_bounds__(512, 4)
void gram_kernel(const float* __restrict__ slots, uint2* __restrict__ p16,
                 unsigned* __restrict__ counter, int D, int nChunks, int G) {
    __shared__ __align__(16) char lds[2][L * PITCH];   // 2 x 16 KB
    const int t    = threadIdx.x;        // 0..511
    const int wave = t >> 6;             // 0..7: wave owns rows [16w, 16w+16)
    const int lane = t & 63;

    if (blockIdx.x == 0 && t == 0) *counter = 0;   // ticket for reduce_finalize

    f32x4 acc[8];
#pragma unroll
    for (int c = 0; c < 8; ++c) acc[c] = (f32x4)0.f;

    float4 ld[4];

    // stage 128 rows x 64 f32: 2048 float4, 512 threads -> 4 each (256 B/row coalesced)
    auto issue = [&](int chunk) {
#pragma unroll
        for (int q = 0; q < 4; ++q) {
            int idx  = t + 512 * q;      // 0..2047
            int row  = idx >> 4;
            int col4 = idx & 15;
            ld[q] = *reinterpret_cast<const float4*>(
                slots + (size_t)row * D + (size_t)chunk * BK + col4 * 4);
        }
    };
    // f32 -> bf16 truncation, XOR-swizzled ds_write_b64 (16 lanes/row -> conflict-free)
    auto commit = [&](int buf) {
#pragma unroll
        for (int q = 0; q < 4; ++q) {
            int idx  = t + 512 * q;
            int row  = idx >> 4;
            int col4 = idx & 15;
            const unsigned* f = reinterpret_cast<const unsigned*>(&ld[q]);
            uint2 w;
            w.x = __builtin_amdgcn_perm(f[1], f[0], 0x07060302u);   // lo=e0 hi=e1
            w.y = __builtin_amdgcn_perm(f[3], f[2], 0x07060302u);   // lo=e2 hi=e3
            int byte = (col4 * 8) ^ ((row & 7) << 4);
            *reinterpret_cast<uint2*>(&lds[buf][row * PITCH + byte]) = w;
        }
    };
    // 8 bf16 of row `row`, k = kk + (lane>>4)*8 .. +7: ONE ds_read_b128, 8-way XOR spread
    auto ldfrag = [&](int buf, int row, int kk) -> bf16x8 {
        int byte = row * PITCH + ((kk * 2 + ((lane >> 4) << 4)) ^ ((row & 7) << 4));
        return *reinterpret_cast<const bf16x8*>(&lds[buf][byte]);
    };

    issue(blockIdx.x);
    commit(0);
    __syncthreads();

    int k = 0;
    for (int c = blockIdx.x; c < nChunks; c += G, ++k) {
        const int cur = k & 1;
        const bool more = (c + G < nChunks);
        if (more) issue(c + G);          // HBM loads in flight across the MFMA phase

#pragma unroll
        for (int kk = 0; kk < BK; kk += 32) {
            bf16x8 a = ldfrag(cur, wave * 16 + (lane & 15), kk);
#pragma unroll
            for (int cc = 0; cc < 8; ++cc) {
                bf16x8 b = ldfrag(cur, cc * 16 + (lane & 15), kk);
                acc[cc] = __builtin_amdgcn_mfma_f32_16x16x32_bf16(a, b, acc[cc], 0, 0, 0);
            }
        }

        if (more) commit(cur ^ 1);       // other buffer; prev-iter barrier made it safe
        __syncthreads();
    }

    // ---- coalesced bf16 partial writeout: uint2 slot j = cc*512 + t ----
    uint2* pb = p16 + (size_t)blockIdx.x * 4096;     // 32 KB per block
#pragma unroll
    for (int cc = 0; cc < 8; ++cc) {
        const unsigned* a = reinterpret_cast<const unsigned*>(&acc[cc]);
        uint2 w;
        w.x = __builtin_amdgcn_perm(a[1], a[0], 0x07060302u);   // lo=reg0 hi=reg1
        w.y = __builtin_amdgcn_perm(a[3], a[2], 0x07060302u);   // lo=reg2 hi=reg3
        pb[cc * 512 + t] = w;
    }
}

// 128 blocks x 256 threads; block owns 32 uint2-slots; 8 sub-groups split the b-range.
// Single-writer gram (no atomics, no zeroing). Last block (ticket) finalizes.
__global__ __launch_bounds__(256)
void reduce_finalize(const uint2* __restrict__ p16, float* __restrict__ gram,
                     unsigned* __restrict__ counter,
                     const float* __restrict__ temperature, float* __restrict__ out,
                     int G) {
    __shared__ f32x4 red[8][32];
    __shared__ float norms[L];
    __shared__ float wred[4];
    __shared__ unsigned ticket_s;
    const int t   = threadIdx.x;
    const int sub = t >> 5;
    const int sl  = t & 31;
    const int j   = blockIdx.x * 32 + sl;       // uint2 slot 0..4095

    f32x4 s = (f32x4)0.f;
#pragma unroll 8
    for (int b = sub; b < G; b += 8) {
        const uint2 u = p16[(size_t)b * 4096 + j];
        s[0] += blo(u.x); s[1] += bhi(u.x);
        s[2] += blo(u.y); s[3] += bhi(u.y);
    }
    red[sub][sl] = s;
    __syncthreads();
    if (t < 32) {
        f32x4 s4 = red[0][t];
#pragma unroll
        for (int w = 1; w < 8; ++w) s4 += red[w][t];
        // decode uint2 slot -> gram coords (matches gram_kernel epilogue)
        const int myj  = blockIdx.x * 32 + t;
        const int cc   = myj >> 9;
        const int tenc = myj & 511;
        const int wv = tenc >> 6, ln = tenc & 63;
        const int growb = wv * 16 + ((ln >> 4) << 2);
        const int gcol  = cc * 16 + (ln & 15);
#pragma unroll
        for (int q = 0; q < 4; ++q) gram[(growb + q) * L + gcol] = s4[q];
    }

    __syncthreads();
    if (t == 0) {
        __threadfence();
        ticket_s = atomicAdd(counter, 1u);
    }
    __syncthreads();
    if (ticket_s != (unsigned)(gridDim.x - 1)) return;
    __threadfence();

    // ---------------- finalize (last block only) ----------------
    if (t < L) norms[t] = sqrtf(gram[t * L + t]);
    __syncthreads();

    const float invT = 1.0f / temperature[0];
    const int r = t >> 1;            // row, 2 threads per row
    const int q = t & 1;
    const float ni = norms[r];

    float ps = 0.f;
    for (int jj = q; jj < L; jj += 2) {
        float sim = gram[r * L + jj] / fmaxf(ni * norms[jj], 1e-6f);
        ps += __expf(sim * invT);
    }
    ps += __shfl_xor(ps, 1);
    const float rowsum = ps;

    float tot = 0.f;
    for (int jj = q; jj < L; jj += 2) {
        if (jj > r) {
            float logit = (gram[r * L + jj] / fmaxf(ni * norms[jj], 1e-6f)) * invT;
            tot += -(logit - __logf(rowsum - __expf(logit))) * (float)(jj - r);
        }
    }
#pragma unroll
    for (int m = 1; m < 64; m <<= 1) tot += __shfl_xor(tot, m);
    if ((t & 63) == 0) wred[t >> 6] = tot;
    __syncthreads();
    if (t == 0)
        out[0] = (wred[0] + wred[1] + wred[2] + wred[3]) /
                 ((float)(L - 1) * (float)(L - 1) * 0.5f);
}

extern "C" void kernel_launch(void* const* d_in, const int* in_sizes, int n_in,
                              void* d_out, int out_size, void* d_ws, size_t ws_size,
                              hipStream_t stream) {
    const float* slots       = (const float*)d_in[0];
    const float* temperature = (const float*)d_in[1];
    float* out  = (float*)d_out;

    const int D = in_sizes[0] / L;                  // 262144
    const int nChunks = D / BK;                     // 4096
    int G = GRID;
    if (G > nChunks) G = nChunks;

    uint2*    p16     = (uint2*)d_ws;                                 // G*32 KB = 16 MB
    float*    gram    = (float*)((char*)d_ws + (size_t)G * 32768);    // 64 KB
    unsigned* counter = (unsigned*)((char*)gram + (size_t)L * L * 4);

    gram_kernel<<<G, 512, 0, stream>>>(slots, p16, counter, D, nChunks, G);
    reduce_finalize<<<128, 256, 0, stream>>>(p16, gram, counter, temperature, out, G);
}